// Round 1
// baseline (374.538 us; speedup 1.0000x reference)
//
#include <hip/hip_runtime.h>
#include <hip/hip_bf16.h>

typedef float f32x4 __attribute__((ext_vector_type(4)));
typedef short s16x8 __attribute__((ext_vector_type(8)));
typedef short s16x4 __attribute__((ext_vector_type(4)));

__device__ __forceinline__ short f2bf(float f) {
  union { float f; unsigned u; } v; v.f = f;
  unsigned r = v.u + 0x7fffu + ((v.u >> 16) & 1u);
  return (short)(r >> 16);
}
__device__ __forceinline__ float bf2f(short s) {
  union { unsigned u; float f; } v; v.u = ((unsigned)(unsigned short)s) << 16;
  return v.f;
}

__device__ __forceinline__ void gload_lds16(const short* g, short* l) {
  __builtin_amdgcn_global_load_lds(
      (const __attribute__((address_space(1))) void*)g,
      (__attribute__((address_space(3))) void*)l, 16, 0, 0);
}

// ---------------- fp32 -> bf16 convert (8 elems/thread) ----------------
__global__ __launch_bounds__(256) void k_f2bf(const float* __restrict__ in,
                                              short* __restrict__ out, int n8) {
  int i = blockIdx.x * 256 + threadIdx.x;
  if (i >= n8) return;
  const float4* p = (const float4*)in + (size_t)i * 2;
  float4 a = p[0], b = p[1];
  s16x8 o;
  o[0] = f2bf(a.x); o[1] = f2bf(a.y); o[2] = f2bf(a.z); o[3] = f2bf(a.w);
  o[4] = f2bf(b.x); o[5] = f2bf(b.y); o[6] = f2bf(b.z); o[7] = f2bf(b.w);
  *(s16x8*)(out + (size_t)i * 8) = o;
}

// ---------------- bf16 GEMM: C[M,N] = A[M,K] @ Bw[N,K]^T ----------------
// 128x128 tile, BK=64, 4 waves (2x2 of 64x64), global_load_lds + XOR swizzle.
// MODE 0: bf16 row-major C.  MODE 1: fp32 row-major C.
// MODE 2: bf16 transposed V: Vt[b][n(512)][t(2048)]  (row m = b*2048+t)
template <int MODE>
__global__ __launch_bounds__(256) void k_gemm_bt(const short* __restrict__ A,
                                                 const short* __restrict__ Bw,
                                                 void* __restrict__ C,
                                                 int M, int N, int K) {
  __shared__ __align__(16) short As[128 * 64];
  __shared__ __align__(16) short Bs[128 * 64];
  const int tid = threadIdx.x;
  const int w = tid >> 6, lane = tid & 63;
  const int wm = w >> 1, wn = w & 1;
  const int bm = blockIdx.y, bn = blockIdx.x;
  const int l15 = lane & 15, l4 = lane >> 4;

  f32x4 acc[4][4] = {};

  const int nk = K >> 6;
  for (int kt = 0; kt < nk; ++kt) {
    __syncthreads();
#pragma unroll
    for (int it = 0; it < 4; ++it) {
      int p = it * 256 + tid;
      int p0 = it * 256 + w * 64;  // wave-uniform chunk base
      int r = p >> 3, j = p & 7;
      int jsrc = j ^ (r & 7);
      gload_lds16(A + (size_t)(bm * 128 + r) * K + kt * 64 + jsrc * 8, &As[p0 * 8]);
      gload_lds16(Bw + (size_t)(bn * 128 + r) * K + kt * 64 + jsrc * 8, &Bs[p0 * 8]);
    }
    __syncthreads();
#pragma unroll
    for (int kk = 0; kk < 2; ++kk) {
      s16x8 af[4], bf[4];
      const int jj = kk * 4 + l4;  // 16B chunk index within row (0..7)
#pragma unroll
      for (int mi = 0; mi < 4; ++mi) {
        int r = wm * 64 + mi * 16 + l15;
        af[mi] = *(const s16x8*)&As[(r * 8 + (jj ^ (r & 7))) * 8];
      }
#pragma unroll
      for (int ni = 0; ni < 4; ++ni) {
        int r = wn * 64 + ni * 16 + l15;
        bf[ni] = *(const s16x8*)&Bs[(r * 8 + (jj ^ (r & 7))) * 8];
      }
#pragma unroll
      for (int mi = 0; mi < 4; ++mi)
#pragma unroll
        for (int ni = 0; ni < 4; ++ni)
          acc[mi][ni] = __builtin_amdgcn_mfma_f32_16x16x32_bf16(
              af[mi], bf[ni], acc[mi][ni], 0, 0, 0);
    }
  }

#pragma unroll
  for (int mi = 0; mi < 4; ++mi) {
#pragma unroll
    for (int ni = 0; ni < 4; ++ni) {
      int row0 = bm * 128 + wm * 64 + mi * 16 + l4 * 4;
      int col = bn * 128 + wn * 64 + ni * 16 + l15;
      if (MODE == 0) {
        short* Cb = (short*)C;
#pragma unroll
        for (int r2 = 0; r2 < 4; ++r2)
          Cb[(size_t)(row0 + r2) * N + col] = f2bf(acc[mi][ni][r2]);
      } else if (MODE == 1) {
        float* Cf = (float*)C;
#pragma unroll
        for (int r2 = 0; r2 < 4; ++r2)
          Cf[(size_t)(row0 + r2) * N + col] = acc[mi][ni][r2];
      } else {
        short* Vt = (short*)C;
        int b = row0 >> 11, t0 = row0 & 2047;
        s16x4 pk;
#pragma unroll
        for (int r2 = 0; r2 < 4; ++r2) pk[r2] = f2bf(acc[mi][ni][r2]);
        *(s16x4*)&Vt[(size_t)b * 1048576 + (size_t)col * 2048 + t0] = pk;
      }
    }
  }
}

// ---------------- RoPE in-place on bf16 Q or K ----------------
// one thread per (row, head, d<64) pair; nheads*64 = 1<<shift
__global__ __launch_bounds__(256) void k_rope(short* __restrict__ X, int shift,
                                              int rowstride) {
  int idx = blockIdx.x * 256 + threadIdx.x;
  int row = idx >> shift;
  int rem = idx & ((1 << shift) - 1);
  int h = rem >> 6, d = rem & 63;
  int t = row & 2047;
  float inv = exp2f(-(float)d * (13.287712379549449f / 64.f));
  float ang = (float)t * inv;
  float s, c;
  sincosf(ang, &s, &c);
  size_t base = (size_t)row * rowstride + h * 128 + d;
  float q0 = bf2f(X[base]), q1 = bf2f(X[base + 64]);
  X[base] = f2bf(q0 * c - q1 * s);
  X[base + 64] = f2bf(q1 * c + q0 * s);
}

// ---------------- flash attention ----------------
// grid (T/64, H, B), 256 threads = 4 waves, wave w owns 16 q rows.
// Q[4096][2048] bf16 (roped), Kb[4096][512] bf16 (roped), Vt[b][512][2048] bf16.
__global__ __launch_bounds__(256) void k_attn(const short* __restrict__ Q,
                                              const short* __restrict__ Kb,
                                              const short* __restrict__ Vt,
                                              short* __restrict__ Y) {
  __shared__ __align__(16) short Ks[64 * 128];   // CH=16 chunks/row, swizzled
  __shared__ __align__(16) short Vs[128 * 64];   // CH=8 chunks/row, swizzled
  __shared__ __align__(16) short Pb[4][16 * 80]; // per-wave P, padded stride 80

  const int tid = threadIdx.x;
  const int w = tid >> 6, lane = tid & 63;
  const int l15 = lane & 15, l4 = lane >> 4;
  const int qt = blockIdx.x, h = blockIdx.y, b = blockIdx.z;
  const int kh = h >> 2;

  // Q fragments (A-operand): lane reads row q0+l15, k chunk l4*8
  s16x8 qf[4];
  const size_t qrow = (size_t)(b * 2048 + qt * 64 + w * 16 + l15);
#pragma unroll
  for (int kk = 0; kk < 4; ++kk)
    qf[kk] = *(const s16x8*)(Q + qrow * 2048 + h * 128 + kk * 32 + l4 * 8);

  f32x4 acc[8] = {};
  float m[4], lsum[4];
#pragma unroll
  for (int r = 0; r < 4; ++r) { m[r] = -1e30f; lsum[r] = 0.f; }

  const float scale = 0.08838834764831845f;  // 1/sqrt(128)
  const int qrow_t0 = qt * 64 + w * 16 + l4 * 4;  // t-index of this lane's row r=0
  const int ntiles = qt + 1;

  for (int tile = 0; tile < ntiles; ++tile) {
    const int kv0 = tile * 64;
    __syncthreads();  // all waves done reading previous K/V tiles
#pragma unroll
    for (int it = 0; it < 4; ++it) {  // stage K: 64 rows x 16 chunks
      int p = it * 256 + tid;
      int p0 = it * 256 + w * 64;
      int r = p >> 4, j = p & 15;
      int jsrc = j ^ (r & 7);
      gload_lds16(Kb + (size_t)(b * 2048 + kv0 + r) * 512 + kh * 128 + jsrc * 8,
                  &Ks[p0 * 8]);
    }
#pragma unroll
    for (int it = 0; it < 4; ++it) {  // stage Vt: 128 rows x 8 chunks
      int p = it * 256 + tid;
      int p0 = it * 256 + w * 64;
      int r = p >> 3, j = p & 7;
      int jsrc = j ^ (r & 7);
      gload_lds16(Vt + (size_t)b * 1048576 + (size_t)(kh * 128 + r) * 2048 +
                      kv0 + jsrc * 8,
                  &Vs[p0 * 8]);
    }
    __syncthreads();  // staging complete (vmcnt(0) drained by barrier)

    // S = Q K^T  (16 x 64 per wave)
    f32x4 s[4] = {};
#pragma unroll
    for (int kk = 0; kk < 4; ++kk) {
      const int jj = kk * 4 + l4;  // chunk 0..15
#pragma unroll
      for (int jt = 0; jt < 4; ++jt) {
        int r = jt * 16 + l15;
        s16x8 kf = *(const s16x8*)&Ks[(r * 16 + (jj ^ (r & 7))) * 8];
        s[jt] = __builtin_amdgcn_mfma_f32_16x16x32_bf16(qf[kk], kf, s[jt], 0, 0, 0);
      }
    }

    // mask + scale + online softmax (16-lane groups hold full rows)
    float alpha[4];
#pragma unroll
    for (int r = 0; r < 4; ++r) {
      int rowt = qrow_t0 + r;
      float mr = -1e30f;
#pragma unroll
      for (int jt = 0; jt < 4; ++jt) {
        int colt = kv0 + jt * 16 + l15;
        float v = s[jt][r] * scale;
        if (colt > rowt) v = -1e30f;
        s[jt][r] = v;
        mr = fmaxf(mr, v);
      }
#pragma unroll
      for (int mk = 1; mk < 16; mk <<= 1) mr = fmaxf(mr, __shfl_xor(mr, mk));
      float mnew = fmaxf(m[r], mr);
      alpha[r] = __expf(m[r] - mnew);
      m[r] = mnew;
      float rs = 0.f;
#pragma unroll
      for (int jt = 0; jt < 4; ++jt) {
        float p = __expf(s[jt][r] - mnew);
        s[jt][r] = p;
        rs += p;
      }
#pragma unroll
      for (int mk = 1; mk < 16; mk <<= 1) rs += __shfl_xor(rs, mk);
      lsum[r] = lsum[r] * alpha[r] + rs;
    }

    // rescale O accumulator
#pragma unroll
    for (int nt = 0; nt < 8; ++nt)
#pragma unroll
      for (int r = 0; r < 4; ++r) acc[nt][r] *= alpha[r];

    // write P (bf16) to per-wave LDS buffer, D-layout -> row-major
    short* P = &Pb[w][0];
#pragma unroll
    for (int jt = 0; jt < 4; ++jt)
#pragma unroll
      for (int r = 0; r < 4; ++r)
        P[(l4 * 4 + r) * 80 + jt * 16 + l15] = f2bf(s[jt][r]);

    // PV: O += P @ V   (B-operand from transposed-V tile, contiguous reads)
#pragma unroll
    for (int kk2 = 0; kk2 < 2; ++kk2) {
      s16x8 pf = *(const s16x8*)&P[l15 * 80 + kk2 * 32 + l4 * 8];
      const int jj = kk2 * 4 + l4;  // chunk 0..7
#pragma unroll
      for (int nt = 0; nt < 8; ++nt) {
        int r = nt * 16 + l15;
        s16x8 vf = *(const s16x8*)&Vs[(r * 8 + (jj ^ (r & 7))) * 8];
        acc[nt] = __builtin_amdgcn_mfma_f32_16x16x32_bf16(pf, vf, acc[nt], 0, 0, 0);
      }
    }
  }

  // epilogue: normalize and store bf16
#pragma unroll
  for (int nt = 0; nt < 8; ++nt) {
#pragma unroll
    for (int r = 0; r < 4; ++r) {
      size_t row = (size_t)(b * 2048 + qrow_t0 + r);
      Y[row * 2048 + h * 128 + nt * 16 + l15] = f2bf(acc[nt][r] / lsum[r]);
    }
  }
}

extern "C" void kernel_launch(void* const* d_in, const int* in_sizes, int n_in,
                              void* d_out, int out_size, void* d_ws, size_t ws_size,
                              hipStream_t stream) {
  (void)in_sizes; (void)n_in; (void)out_size; (void)ws_size;
  const float* x  = (const float*)d_in[0];
  const float* Wq = (const float*)d_in[1];
  const float* Wk = (const float*)d_in[2];
  const float* Wv = (const float*)d_in[3];
  const float* Wo = (const float*)d_in[4];

  char* ws = (char*)d_ws;
  short* xb  = (short*)(ws);               // 4096x2048 bf16  (16 MiB)
  short* wqb = (short*)(ws + 16777216);    // 2048x2048       (8 MiB)
  short* wkb = (short*)(ws + 25165824);    // 512x2048        (2 MiB)
  short* wvb = (short*)(ws + 27262976);    // 512x2048        (2 MiB)
  short* wob = (short*)(ws + 29360128);    // 2048x2048       (8 MiB)
  short* Qb  = (short*)(ws + 37748736);    // 4096x2048       (16 MiB)
  short* Kb  = (short*)(ws + 54525952);    // 4096x512        (4 MiB)
  short* Vtb = (short*)(ws + 58720256);    // 2x512x2048      (4 MiB)
  short* Yb  = (short*)(ws + 62914560);    // 4096x2048       (16 MiB)

  k_f2bf<<<4096, 256, 0, stream>>>(x, xb, 1048576);
  k_f2bf<<<2048, 256, 0, stream>>>(Wq, wqb, 524288);
  k_f2bf<<<512, 256, 0, stream>>>(Wk, wkb, 131072);
  k_f2bf<<<512, 256, 0, stream>>>(Wv, wvb, 131072);
  k_f2bf<<<2048, 256, 0, stream>>>(Wo, wob, 524288);

  k_gemm_bt<0><<<dim3(16, 32), 256, 0, stream>>>(xb, wqb, Qb, 4096, 2048, 2048);
  k_gemm_bt<0><<<dim3(4, 32), 256, 0, stream>>>(xb, wkb, Kb, 4096, 512, 2048);
  k_gemm_bt<2><<<dim3(4, 32), 256, 0, stream>>>(xb, wvb, Vtb, 4096, 512, 2048);

  k_rope<<<16384, 256, 0, stream>>>(Qb, 10, 2048);
  k_rope<<<4096, 256, 0, stream>>>(Kb, 8, 512);

  k_attn<<<dim3(32, 16, 2), 256, 0, stream>>>(Qb, Kb, Vtb, Yb);

  k_gemm_bt<1><<<dim3(16, 32), 256, 0, stream>>>(Yb, wob, d_out, 4096, 2048, 2048);
}

// Round 2
// 236.132 us; speedup vs baseline: 1.5861x; 1.5861x over previous
//
#include <hip/hip_runtime.h>
#include <hip/hip_bf16.h>

typedef float f32x4 __attribute__((ext_vector_type(4)));
typedef short s16x8 __attribute__((ext_vector_type(8)));
typedef short s16x4 __attribute__((ext_vector_type(4)));

__device__ __forceinline__ short f2bf(float f) {
  union { float f; unsigned u; } v; v.f = f;
  unsigned r = v.u + 0x7fffu + ((v.u >> 16) & 1u);
  return (short)(r >> 16);
}
__device__ __forceinline__ float bf2f(short s) {
  union { unsigned u; float f; } v; v.u = ((unsigned)(unsigned short)s) << 16;
  return v.f;
}

__device__ __forceinline__ void gload_lds16(const short* g, short* l) {
  __builtin_amdgcn_global_load_lds(
      (const __attribute__((address_space(1))) void*)g,
      (__attribute__((address_space(3))) void*)l, 16, 0, 0);
}

// ---------------- fp32 -> bf16 convert (8 elems/thread) ----------------
__global__ __launch_bounds__(256) void k_f2bf(const float* __restrict__ in,
                                              short* __restrict__ out, int n8) {
  int i = blockIdx.x * 256 + threadIdx.x;
  if (i >= n8) return;
  const float4* p = (const float4*)in + (size_t)i * 2;
  float4 a = p[0], b = p[1];
  s16x8 o;
  o[0] = f2bf(a.x); o[1] = f2bf(a.y); o[2] = f2bf(a.z); o[3] = f2bf(a.w);
  o[4] = f2bf(b.x); o[5] = f2bf(b.y); o[6] = f2bf(b.z); o[7] = f2bf(b.w);
  *(s16x8*)(out + (size_t)i * 8) = o;
}

// ---------------- bf16 GEMM: C[M,N] = A[M,K] @ Bw[N,K]^T ----------------
// 128x128 tile, BK=64, 4 waves, global_load_lds + XOR swizzle.
// MODE 1: fp32 row-major C.
// MODE 3: fused QKV epilogue: col<2048 -> Q[4096][2048]; col<2560 ->
//         K[4096][512]; else V transposed Vt[b][n][t].
template <int MODE>
__global__ __launch_bounds__(256) void k_gemm_bt(const short* __restrict__ A,
                                                 const short* __restrict__ Bw,
                                                 void* __restrict__ C,
                                                 void* __restrict__ C2,
                                                 void* __restrict__ C3,
                                                 int M, int N, int K) {
  __shared__ __align__(16) short As[128 * 64];
  __shared__ __align__(16) short Bs[128 * 64];
  const int tid = threadIdx.x;
  const int w = tid >> 6, lane = tid & 63;
  const int wm = w >> 1, wn = w & 1;
  const int bm = blockIdx.y, bn = blockIdx.x;
  const int l15 = lane & 15, l4 = lane >> 4;

  f32x4 acc[4][4] = {};

  const int nk = K >> 6;
  for (int kt = 0; kt < nk; ++kt) {
    __syncthreads();
#pragma unroll
    for (int it = 0; it < 4; ++it) {
      int p = it * 256 + tid;
      int p0 = it * 256 + w * 64;  // wave-uniform chunk base
      int r = p >> 3, j = p & 7;
      int jsrc = j ^ (r & 7);
      gload_lds16(A + (size_t)(bm * 128 + r) * K + kt * 64 + jsrc * 8, &As[p0 * 8]);
      gload_lds16(Bw + (size_t)(bn * 128 + r) * K + kt * 64 + jsrc * 8, &Bs[p0 * 8]);
    }
    __syncthreads();
#pragma unroll
    for (int kk = 0; kk < 2; ++kk) {
      s16x8 af[4], bf[4];
      const int jj = kk * 4 + l4;
#pragma unroll
      for (int mi = 0; mi < 4; ++mi) {
        int r = wm * 64 + mi * 16 + l15;
        af[mi] = *(const s16x8*)&As[(r * 8 + (jj ^ (r & 7))) * 8];
      }
#pragma unroll
      for (int ni = 0; ni < 4; ++ni) {
        int r = wn * 64 + ni * 16 + l15;
        bf[ni] = *(const s16x8*)&Bs[(r * 8 + (jj ^ (r & 7))) * 8];
      }
      __builtin_amdgcn_s_setprio(1);
#pragma unroll
      for (int mi = 0; mi < 4; ++mi)
#pragma unroll
        for (int ni = 0; ni < 4; ++ni)
          acc[mi][ni] = __builtin_amdgcn_mfma_f32_16x16x32_bf16(
              af[mi], bf[ni], acc[mi][ni], 0, 0, 0);
      __builtin_amdgcn_s_setprio(0);
    }
  }

#pragma unroll
  for (int mi = 0; mi < 4; ++mi) {
#pragma unroll
    for (int ni = 0; ni < 4; ++ni) {
      int row0 = bm * 128 + wm * 64 + mi * 16 + l4 * 4;
      int col = bn * 128 + wn * 64 + ni * 16 + l15;
      if (MODE == 1) {
        float* Cf = (float*)C;
#pragma unroll
        for (int r2 = 0; r2 < 4; ++r2)
          Cf[(size_t)(row0 + r2) * N + col] = acc[mi][ni][r2];
      } else {  // MODE 3: fused QKV
        if (col < 2048) {
          short* Qo = (short*)C;
#pragma unroll
          for (int r2 = 0; r2 < 4; ++r2)
            Qo[(size_t)(row0 + r2) * 2048 + col] = f2bf(acc[mi][ni][r2]);
        } else if (col < 2560) {
          short* Ko = (short*)C2;
#pragma unroll
          for (int r2 = 0; r2 < 4; ++r2)
            Ko[(size_t)(row0 + r2) * 512 + (col - 2048)] = f2bf(acc[mi][ni][r2]);
        } else {
          short* Vo = (short*)C3;
          int b = row0 >> 11, t0 = row0 & 2047;
          s16x4 pk;
#pragma unroll
          for (int r2 = 0; r2 < 4; ++r2) pk[r2] = f2bf(acc[mi][ni][r2]);
          *(s16x4*)&Vo[(size_t)b * 1048576 + (size_t)(col - 2560) * 2048 + t0] = pk;
        }
      }
    }
  }
}

// ---------------- RoPE in-place on bf16 Q or K (with output scale) --------
__global__ __launch_bounds__(256) void k_rope(short* __restrict__ X, int shift,
                                              int rowstride, float mul) {
  int idx = blockIdx.x * 256 + threadIdx.x;
  int row = idx >> shift;
  int rem = idx & ((1 << shift) - 1);
  int h = rem >> 6, d = rem & 63;
  int t = row & 2047;
  float inv = exp2f(-(float)d * (13.287712379549449f / 64.f));
  float ang = (float)t * inv;
  float s, c;
  sincosf(ang, &s, &c);
  size_t base = (size_t)row * rowstride + h * 128 + d;
  float q0 = bf2f(X[base]), q1 = bf2f(X[base + 64]);
  X[base] = f2bf((q0 * c - q1 * s) * mul);
  X[base + 64] = f2bf((q1 * c + q0 * s) * mul);
}

// ---------------- flash attention, paired q-tiles + double-buffered K/V ----
// Q pre-scaled by (1/sqrt(d))*log2(e) so softmax uses exp2 directly.
__device__ __forceinline__ void attn_tile(const s16x8* qf, const short* Ksb,
                                          const short* Vsb, short* P,
                                          f32x4* acc, float* m, float* lsum,
                                          bool diag, int rt0, int l15, int l4) {
  f32x4 s[4] = {};
  __builtin_amdgcn_s_setprio(1);
#pragma unroll
  for (int kk = 0; kk < 4; ++kk) {
    const int jj = kk * 4 + l4;
#pragma unroll
    for (int jt = 0; jt < 4; ++jt) {
      int r = jt * 16 + l15;
      s16x8 kf = *(const s16x8*)&Ksb[(r * 16 + (jj ^ (r & 7))) * 8];
      s[jt] = __builtin_amdgcn_mfma_f32_16x16x32_bf16(qf[kk], kf, s[jt], 0, 0, 0);
    }
  }
  __builtin_amdgcn_s_setprio(0);

  float alpha[4];
#pragma unroll
  for (int r = 0; r < 4; ++r) {
    if (diag) {
#pragma unroll
      for (int jt = 0; jt < 4; ++jt)
        if (jt * 16 + l15 > rt0 + r) s[jt][r] = -1e30f;
    }
    float mr = fmaxf(fmaxf(s[0][r], s[1][r]), fmaxf(s[2][r], s[3][r]));
#pragma unroll
    for (int mk = 1; mk < 16; mk <<= 1) mr = fmaxf(mr, __shfl_xor(mr, mk));
    float mnew = fmaxf(m[r], mr);
    alpha[r] = exp2f(m[r] - mnew);
    m[r] = mnew;
    float rs = 0.f;
#pragma unroll
    for (int jt = 0; jt < 4; ++jt) {
      float p = exp2f(s[jt][r] - mnew);
      s[jt][r] = p;
      rs += p;
    }
#pragma unroll
    for (int mk = 1; mk < 16; mk <<= 1) rs += __shfl_xor(rs, mk);
    lsum[r] = lsum[r] * alpha[r] + rs;
  }

#pragma unroll
  for (int nt = 0; nt < 8; ++nt)
#pragma unroll
    for (int r = 0; r < 4; ++r) acc[nt][r] *= alpha[r];

#pragma unroll
  for (int jt = 0; jt < 4; ++jt)
#pragma unroll
    for (int r = 0; r < 4; ++r)
      P[(l4 * 4 + r) * 80 + jt * 16 + l15] = f2bf(s[jt][r]);

#pragma unroll
  for (int kk2 = 0; kk2 < 2; ++kk2) {
    s16x8 pf = *(const s16x8*)&P[l15 * 80 + kk2 * 32 + l4 * 8];
    const int jj = kk2 * 4 + l4;
    __builtin_amdgcn_s_setprio(1);
#pragma unroll
    for (int nt = 0; nt < 8; ++nt) {
      int r = nt * 16 + l15;
      s16x8 vf = *(const s16x8*)&Vsb[(r * 8 + (jj ^ (r & 7))) * 8];
      acc[nt] = __builtin_amdgcn_mfma_f32_16x16x32_bf16(pf, vf, acc[nt], 0, 0, 0);
    }
    __builtin_amdgcn_s_setprio(0);
  }
}

// grid (16 pair, 16 h, 2 b), 256 threads = 4 waves.
// Block handles q-tiles qtA=pair and qtB=31-pair: uniform 33 tile-computes.
__global__ __launch_bounds__(256, 2) void k_attn2(const short* __restrict__ Q,
                                                  const short* __restrict__ Kb,
                                                  const short* __restrict__ Vt,
                                                  short* __restrict__ Y) {
  __shared__ __align__(16) short Ks[2][64 * 128];
  __shared__ __align__(16) short Vs[2][128 * 64];
  __shared__ __align__(16) short Pb[4][16 * 80];

  const int tid = threadIdx.x;
  const int w = tid >> 6, lane = tid & 63;
  const int l15 = lane & 15, l4 = lane >> 4;
  const int pair = blockIdx.x, h = blockIdx.y, b = blockIdx.z;
  const int kh = h >> 2;
  const int qtA = pair, qtB = 31 - pair;

  s16x8 qfA[4], qfB[4];
  {
    const size_t rowA = (size_t)(b * 2048 + qtA * 64 + w * 16 + l15);
    const size_t rowB = (size_t)(b * 2048 + qtB * 64 + w * 16 + l15);
#pragma unroll
    for (int kk = 0; kk < 4; ++kk) {
      qfA[kk] = *(const s16x8*)(Q + rowA * 2048 + h * 128 + kk * 32 + l4 * 8);
      qfB[kk] = *(const s16x8*)(Q + rowB * 2048 + h * 128 + kk * 32 + l4 * 8);
    }
  }

  f32x4 accA[8] = {}, accB[8] = {};
  float mA[4], mB[4], lA[4], lB[4];
#pragma unroll
  for (int r = 0; r < 4; ++r) {
    mA[r] = -1e30f; mB[r] = -1e30f; lA[r] = 0.f; lB[r] = 0.f;
  }

  auto stage = [&](int buf, int j) {
    const int kv0 = j * 64;
#pragma unroll
    for (int it = 0; it < 4; ++it) {  // K tile: 64 rows x 16 chunks
      int p = it * 256 + tid;
      int p0 = it * 256 + w * 64;
      int r = p >> 4, jc = p & 15;
      int jsrc = jc ^ (r & 7);
      gload_lds16(Kb + (size_t)(b * 2048 + kv0 + r) * 512 + kh * 128 + jsrc * 8,
                  &Ks[buf][p0 * 8]);
    }
#pragma unroll
    for (int it = 0; it < 4; ++it) {  // V^T tile: 128 d-rows x 8 chunks
      int p = it * 256 + tid;
      int p0 = it * 256 + w * 64;
      int r = p >> 3, jc = p & 7;
      int jsrc = jc ^ (r & 7);
      gload_lds16(Vt + (size_t)b * 1048576 + (size_t)(kh * 128 + r) * 2048 +
                      kv0 + jsrc * 8,
                  &Vs[buf][p0 * 8]);
    }
  };

  const int rt0 = w * 16 + l4 * 4;
  const int nt = qtB + 1;

  stage(0, 0);
  __syncthreads();  // prologue drain

  for (int j = 0; j < nt; ++j) {
    const int cur = j & 1;
    if (j + 1 < nt) stage(cur ^ 1, j + 1);  // prefetch next tile
    attn_tile(qfB, &Ks[cur][0], &Vs[cur][0], &Pb[w][0], accB, mB, lB,
              j == qtB, rt0, l15, l4);
    if (j <= qtA)
      attn_tile(qfA, &Ks[cur][0], &Vs[cur][0], &Pb[w][0], accA, mA, lA,
                j == qtA, rt0, l15, l4);
    __syncthreads();  // drains this wave's prefetch (vmcnt0) + buffer handoff
  }

#pragma unroll
  for (int ntd = 0; ntd < 8; ++ntd) {
#pragma unroll
    for (int r = 0; r < 4; ++r) {
      size_t rA = (size_t)(b * 2048 + qtA * 64 + rt0 + r);
      size_t rB = (size_t)(b * 2048 + qtB * 64 + rt0 + r);
      Y[rA * 2048 + h * 128 + ntd * 16 + l15] = f2bf(accA[ntd][r] / lA[r]);
      Y[rB * 2048 + h * 128 + ntd * 16 + l15] = f2bf(accB[ntd][r] / lB[r]);
    }
  }
}

extern "C" void kernel_launch(void* const* d_in, const int* in_sizes, int n_in,
                              void* d_out, int out_size, void* d_ws, size_t ws_size,
                              hipStream_t stream) {
  (void)in_sizes; (void)n_in; (void)out_size; (void)ws_size;
  const float* x  = (const float*)d_in[0];
  const float* Wq = (const float*)d_in[1];
  const float* Wk = (const float*)d_in[2];
  const float* Wv = (const float*)d_in[3];
  const float* Wo = (const float*)d_in[4];

  char* ws = (char*)d_ws;
  short* xb    = (short*)(ws);              // 4096x2048 bf16 (16 MiB)
  short* wqkvb = (short*)(ws + 16777216);   // 3072x2048      (12 MiB)
  short* wob   = (short*)(ws + 29360128);   // 2048x2048      (8 MiB)
  short* Qb    = (short*)(ws + 37748736);   // 4096x2048      (16 MiB)
  short* Kb    = (short*)(ws + 54525952);   // 4096x512       (4 MiB)
  short* Vtb   = (short*)(ws + 58720256);   // 2x512x2048     (4 MiB)
  short* Yb    = (short*)(ws + 62914560);   // 4096x2048      (16 MiB)

  k_f2bf<<<4096, 256, 0, stream>>>(x, xb, 1048576);
  k_f2bf<<<2048, 256, 0, stream>>>(Wq, wqkvb, 524288);
  k_f2bf<<<512, 256, 0, stream>>>(Wk, wqkvb + 4194304, 131072);
  k_f2bf<<<512, 256, 0, stream>>>(Wv, wqkvb + 5242880, 131072);
  k_f2bf<<<2048, 256, 0, stream>>>(Wo, wob, 524288);

  // fused QKV projection: N = 2048(Q) + 512(K) + 512(V) = 3072
  k_gemm_bt<3><<<dim3(24, 32), 256, 0, stream>>>(xb, wqkvb, Qb, Kb, Vtb,
                                                 4096, 3072, 2048);

  // RoPE; Q gets (1/sqrt(128))*log2(e) folded in for exp2-domain softmax
  k_rope<<<16384, 256, 0, stream>>>(Qb, 10, 2048, 0.12751758912141852f);
  k_rope<<<4096, 256, 0, stream>>>(Kb, 8, 512, 1.0f);

  k_attn2<<<dim3(16, 16, 2), 256, 0, stream>>>(Qb, Kb, Vtb, Yb);

  k_gemm_bt<1><<<dim3(16, 32), 256, 0, stream>>>(Yb, wob, d_out, nullptr,
                                                 nullptr, 4096, 2048, 2048);
}

// Round 3
// 211.242 us; speedup vs baseline: 1.7730x; 1.1178x over previous
//
#include <hip/hip_runtime.h>
#include <hip/hip_bf16.h>

typedef float f32x4 __attribute__((ext_vector_type(4)));
typedef float f32x16 __attribute__((ext_vector_type(16)));
typedef short s16x8 __attribute__((ext_vector_type(8)));
typedef short s16x4 __attribute__((ext_vector_type(4)));

__device__ __forceinline__ short f2bf(float f) {
  union { float f; unsigned u; } v; v.f = f;
  unsigned r = v.u + 0x7fffu + ((v.u >> 16) & 1u);
  return (short)(r >> 16);
}
__device__ __forceinline__ float bf2f(short s) {
  union { unsigned u; float f; } v; v.u = ((unsigned)(unsigned short)s) << 16;
  return v.f;
}
__device__ __forceinline__ unsigned cvtpk(float lo, float hi) {
  unsigned r;
  asm("v_cvt_pk_bf16_f32 %0, %1, %2" : "=v"(r) : "v"(lo), "v"(hi));
  return r;
}

__device__ __forceinline__ void gload_lds16(const short* g, short* l) {
  __builtin_amdgcn_global_load_lds(
      (const __attribute__((address_space(1))) void*)g,
      (__attribute__((address_space(3))) void*)l, 16, 0, 0);
}

// ---------------- fp32 -> bf16 convert (8 elems/thread) ----------------
__global__ __launch_bounds__(256) void k_f2bf(const float* __restrict__ in,
                                              short* __restrict__ out, int n8) {
  int i = blockIdx.x * 256 + threadIdx.x;
  if (i >= n8) return;
  const float4* p = (const float4*)in + (size_t)i * 2;
  float4 a = p[0], b = p[1];
  s16x8 o;
  o[0] = f2bf(a.x); o[1] = f2bf(a.y); o[2] = f2bf(a.z); o[3] = f2bf(a.w);
  o[4] = f2bf(b.x); o[5] = f2bf(b.y); o[6] = f2bf(b.z); o[7] = f2bf(b.w);
  *(s16x8*)(out + (size_t)i * 8) = o;
}

// ---------------- bf16 GEMM: C[M,N] = A[M,K] @ Bw[N,K]^T ----------------
// MODE 1: fp32 row-major C.  MODE 3: fused QKV epilogue.
template <int MODE>
__global__ __launch_bounds__(256) void k_gemm_bt(const short* __restrict__ A,
                                                 const short* __restrict__ Bw,
                                                 void* __restrict__ C,
                                                 void* __restrict__ C2,
                                                 void* __restrict__ C3,
                                                 int M, int N, int K) {
  __shared__ __align__(16) short As[128 * 64];
  __shared__ __align__(16) short Bs[128 * 64];
  const int tid = threadIdx.x;
  const int w = tid >> 6, lane = tid & 63;
  const int wm = w >> 1, wn = w & 1;
  const int bm = blockIdx.y, bn = blockIdx.x;
  const int l15 = lane & 15, l4 = lane >> 4;

  f32x4 acc[4][4] = {};

  const int nk = K >> 6;
  for (int kt = 0; kt < nk; ++kt) {
    __syncthreads();
#pragma unroll
    for (int it = 0; it < 4; ++it) {
      int p = it * 256 + tid;
      int p0 = it * 256 + w * 64;
      int r = p >> 3, j = p & 7;
      int jsrc = j ^ (r & 7);
      gload_lds16(A + (size_t)(bm * 128 + r) * K + kt * 64 + jsrc * 8, &As[p0 * 8]);
      gload_lds16(Bw + (size_t)(bn * 128 + r) * K + kt * 64 + jsrc * 8, &Bs[p0 * 8]);
    }
    __syncthreads();
#pragma unroll
    for (int kk = 0; kk < 2; ++kk) {
      s16x8 af[4], bf[4];
      const int jj = kk * 4 + l4;
#pragma unroll
      for (int mi = 0; mi < 4; ++mi) {
        int r = wm * 64 + mi * 16 + l15;
        af[mi] = *(const s16x8*)&As[(r * 8 + (jj ^ (r & 7))) * 8];
      }
#pragma unroll
      for (int ni = 0; ni < 4; ++ni) {
        int r = wn * 64 + ni * 16 + l15;
        bf[ni] = *(const s16x8*)&Bs[(r * 8 + (jj ^ (r & 7))) * 8];
      }
      __builtin_amdgcn_s_setprio(1);
#pragma unroll
      for (int mi = 0; mi < 4; ++mi)
#pragma unroll
        for (int ni = 0; ni < 4; ++ni)
          acc[mi][ni] = __builtin_amdgcn_mfma_f32_16x16x32_bf16(
              af[mi], bf[ni], acc[mi][ni], 0, 0, 0);
      __builtin_amdgcn_s_setprio(0);
    }
  }

#pragma unroll
  for (int mi = 0; mi < 4; ++mi) {
#pragma unroll
    for (int ni = 0; ni < 4; ++ni) {
      int row0 = bm * 128 + wm * 64 + mi * 16 + l4 * 4;
      int col = bn * 128 + wn * 64 + ni * 16 + l15;
      if (MODE == 1) {
        float* Cf = (float*)C;
#pragma unroll
        for (int r2 = 0; r2 < 4; ++r2)
          Cf[(size_t)(row0 + r2) * N + col] = acc[mi][ni][r2];
      } else {  // MODE 3: fused QKV
        if (col < 2048) {
          short* Qo = (short*)C;
#pragma unroll
          for (int r2 = 0; r2 < 4; ++r2)
            Qo[(size_t)(row0 + r2) * 2048 + col] = f2bf(acc[mi][ni][r2]);
        } else if (col < 2560) {
          short* Ko = (short*)C2;
#pragma unroll
          for (int r2 = 0; r2 < 4; ++r2)
            Ko[(size_t)(row0 + r2) * 512 + (col - 2048)] = f2bf(acc[mi][ni][r2]);
        } else {
          short* Vo = (short*)C3;
          int b = row0 >> 11, t0 = row0 & 2047;
          s16x4 pk;
#pragma unroll
          for (int r2 = 0; r2 < 4; ++r2) pk[r2] = f2bf(acc[mi][ni][r2]);
          *(s16x4*)&Vo[(size_t)b * 1048576 + (size_t)(col - 2560) * 2048 + t0] = pk;
        }
      }
    }
  }
}

// ---------------- RoPE in-place on bf16 Q or K (with output scale) --------
__global__ __launch_bounds__(256) void k_rope(short* __restrict__ X, int shift,
                                              int rowstride, float mul) {
  int idx = blockIdx.x * 256 + threadIdx.x;
  int row = idx >> shift;
  int rem = idx & ((1 << shift) - 1);
  int h = rem >> 6, d = rem & 63;
  int t = row & 2047;
  float inv = exp2f(-(float)d * (13.287712379549449f / 64.f));
  float ang = (float)t * inv;
  float s, c;
  sincosf(ang, &s, &c);
  size_t base = (size_t)row * rowstride + h * 128 + d;
  float q0 = bf2f(X[base]), q1 = bf2f(X[base + 64]);
  X[base] = f2bf((q0 * c - q1 * s) * mul);
  X[base + 64] = f2bf((q1 * c + q0 * s) * mul);
}

// ---------------- flash attention, 32x32 MFMA, swapped operands ----------
// 4 waves x 32 q-cols = 128 q-rows/block. KVBLK=64 double-buffered.
// S^T = mfma(K, Q): lane owns full q-row (col=l31) -> in-register softmax.
// O^T = mfma(V^T, P^T): P relayout via cvt_pk + shfl_xor(32).
// Q pre-scaled by log2(e)/sqrt(d): softmax in exp2 domain, defer-max THR=8.
__global__ __launch_bounds__(256, 2) void k_attn3(const short* __restrict__ Q,
                                                  const short* __restrict__ Kb,
                                                  const short* __restrict__ Vt,
                                                  short* __restrict__ Y) {
  __shared__ __align__(16) short Ks[2][64 * 128];  // 16 chunks/row, add-rotate
  __shared__ __align__(16) short Vs[2][128 * 64];  // 8 chunks/row, add-rotate

  const int tid = threadIdx.x;
  const int w = tid >> 6, lane = tid & 63;
  const int l31 = lane & 31, h5 = lane >> 5;
  const int qx = blockIdx.x, h = blockIdx.y, b = blockIdx.z;
  const int qi = b ? (15 - qx) : qx;  // complementary load across batch halves
  const int kh = h >> 2;

  // Q as B-operand fragments (8 frags over D=128): lane = q-col l31
  s16x8 qf[8];
  const int qrow_local = qi * 128 + w * 32 + l31;
  const size_t qrow = (size_t)(b * 2048 + qrow_local);
#pragma unroll
  for (int f = 0; f < 8; ++f)
    qf[f] = *(const s16x8*)(Q + qrow * 2048 + h * 128 + f * 16 + h5 * 8);

  f32x16 oacc[4] = {};
  float m = -1e30f, l = 0.f;

  const int jmax = 2 * qi + 1;

  auto stage = [&](int buf, int j) {
#pragma unroll
    for (int it = 0; it < 4; ++it) {  // K: 64 rows x 16 chunks
      int p = it * 256 + tid;
      int p0 = it * 256 + w * 64;
      int r = p >> 4, c = p & 15;
      int csrc = (c - r) & 15;
      gload_lds16(Kb + (size_t)(b * 2048 + j * 64 + r) * 512 + kh * 128 + csrc * 8,
                  &Ks[buf][p0 * 8]);
    }
#pragma unroll
    for (int it = 0; it < 4; ++it) {  // V^T: 128 d-rows x 8 chunks
      int p = it * 256 + tid;
      int p0 = it * 256 + w * 64;
      int r = p >> 3, c = p & 7;
      int csrc = (c - r) & 7;
      gload_lds16(Vt + (size_t)b * 1048576 + (size_t)(kh * 128 + r) * 2048 +
                      j * 64 + csrc * 8,
                  &Vs[buf][p0 * 8]);
    }
  };

  stage(0, 0);
  __syncthreads();

  for (int j = 0; j <= jmax; ++j) {
    const int cur = j & 1;
    if (j < jmax) stage(cur ^ 1, j + 1);

    // ---- S^T = K @ Q : lane holds 32 k-values of q-row l31 ----
    f32x16 sa0 = {}, sa1 = {};
    __builtin_amdgcn_s_setprio(1);
#pragma unroll
    for (int f = 0; f < 8; ++f) {
      int c = f * 2 + h5;
      int r0 = l31, r1 = 32 + l31;
      s16x8 k0 = *(const s16x8*)&Ks[cur][(r0 * 16 + ((c + r0) & 15)) * 8];
      s16x8 k1 = *(const s16x8*)&Ks[cur][(r1 * 16 + ((c + r1) & 15)) * 8];
      sa0 = __builtin_amdgcn_mfma_f32_32x32x16_bf16(k0, qf[f], sa0, 0, 0, 0);
      sa1 = __builtin_amdgcn_mfma_f32_32x32x16_bf16(k1, qf[f], sa1, 0, 0, 0);
    }
    __builtin_amdgcn_s_setprio(0);

    // ---- causal mask (only on/past the diagonal band) ----
    if (j >= 2 * qi) {
      const int kv0 = j * 64;
#pragma unroll
      for (int rg = 0; rg < 16; ++rg) {
        int krow = (rg & 3) + 8 * (rg >> 2) + 4 * h5;
        if (kv0 + krow > qrow_local) sa0[rg] = -3.0e38f;
        if (kv0 + 32 + krow > qrow_local) sa1[rg] = -3.0e38f;
      }
    }

    // ---- in-register online softmax (exp2 domain) ----
    float mx[16];
#pragma unroll
    for (int i = 0; i < 16; ++i) mx[i] = fmaxf(sa0[i], sa1[i]);
#pragma unroll
    for (int stp = 8; stp > 0; stp >>= 1)
#pragma unroll
      for (int i = 0; i < stp; ++i) mx[i] = fmaxf(mx[i], mx[i + stp]);
    float pm = fmaxf(mx[0], __shfl_xor(mx[0], 32));

    if (!__all(pm - m <= 8.f)) {  // defer-max (T13)
      float mn = fmaxf(m, pm);
      float al = exp2f(m - mn);
      m = mn;
      l *= al;
#pragma unroll
      for (int d = 0; d < 4; ++d)
#pragma unroll
        for (int i = 0; i < 16; ++i) oacc[d][i] *= al;
    }

    float sm[16];
#pragma unroll
    for (int i = 0; i < 16; ++i) {
      float e0 = exp2f(sa0[i] - m);
      float e1 = exp2f(sa1[i] - m);
      sa0[i] = e0; sa1[i] = e1;
      sm[i] = e0 + e1;
    }
#pragma unroll
    for (int stp = 8; stp > 0; stp >>= 1)
#pragma unroll
      for (int i = 0; i < stp; ++i) sm[i] += sm[i + stp];
    l += sm[0] + __shfl_xor(sm[0], 32);

    // ---- P -> bf16 B-operand fragments (in-register relayout) ----
    // lane holds k = a*32 + (rg&3) + 8*(rg>>2) + 4*h5; B-frag f needs
    // k = f*16 + h5*8 + {0..7}: e<4 from h5=0 half, e>=4 from h5=1 half.
    unsigned u0[8], u1[8];
#pragma unroll
    for (int g = 0; g < 4; ++g) {
      u0[2 * g]     = cvtpk(sa0[4 * g + 0], sa0[4 * g + 1]);
      u0[2 * g + 1] = cvtpk(sa0[4 * g + 2], sa0[4 * g + 3]);
      u1[2 * g]     = cvtpk(sa1[4 * g + 0], sa1[4 * g + 1]);
      u1[2 * g + 1] = cvtpk(sa1[4 * g + 2], sa1[4 * g + 3]);
    }
    unsigned pu0[8], pu1[8];
#pragma unroll
    for (int g2 = 0; g2 < 8; ++g2) {
      pu0[g2] = __shfl_xor(u0[g2], 32);
      pu1[g2] = __shfl_xor(u1[g2], 32);
    }
    s16x8 pb[4];
#pragma unroll
    for (int fp = 0; fp < 4; ++fp) {
      int j0a = (4 * fp) & 6, j0b = (4 * fp + 2) & 6;
      union { unsigned uu[4]; s16x8 v; } cv;
      if (fp < 2) {
        cv.uu[0] = h5 ? pu0[j0b]     : u0[j0a];
        cv.uu[1] = h5 ? pu0[j0b + 1] : u0[j0a + 1];
        cv.uu[2] = h5 ? u0[j0b]      : pu0[j0a];
        cv.uu[3] = h5 ? u0[j0b + 1]  : pu0[j0a + 1];
      } else {
        cv.uu[0] = h5 ? pu1[j0b]     : u1[j0a];
        cv.uu[1] = h5 ? pu1[j0b + 1] : u1[j0a + 1];
        cv.uu[2] = h5 ? u1[j0b]      : pu1[j0a];
        cv.uu[3] = h5 ? u1[j0b + 1]  : pu1[j0a + 1];
      }
      pb[fp] = cv.v;
    }

    // ---- O^T += V^T @ P^T ----
    __builtin_amdgcn_s_setprio(1);
#pragma unroll
    for (int dblk = 0; dblk < 4; ++dblk) {
#pragma unroll
      for (int fp = 0; fp < 4; ++fp) {
        int r = dblk * 32 + l31;
        int slot = (fp * 2 + h5 + r) & 7;
        s16x8 vf = *(const s16x8*)&Vs[cur][(r * 8 + slot) * 8];
        oacc[dblk] = __builtin_amdgcn_mfma_f32_32x32x16_bf16(vf, pb[fp],
                                                             oacc[dblk], 0, 0, 0);
      }
    }
    __builtin_amdgcn_s_setprio(0);

    __syncthreads();  // buffer handoff + drains this tile's prefetch
  }

  // ---- epilogue: normalize, pack, 8B stores ----
  float inv = 1.f / l;
#pragma unroll
  for (int dblk = 0; dblk < 4; ++dblk) {
#pragma unroll
    for (int rg = 0; rg < 4; ++rg) {
      unsigned lo = cvtpk(oacc[dblk][4 * rg + 0] * inv, oacc[dblk][4 * rg + 1] * inv);
      unsigned hi = cvtpk(oacc[dblk][4 * rg + 2] * inv, oacc[dblk][4 * rg + 3] * inv);
      int d0 = dblk * 32 + 8 * rg + 4 * h5;
      uint2 st;
      st.x = lo; st.y = hi;
      *(uint2*)(Y + qrow * 2048 + h * 128 + d0) = st;
    }
  }
}

extern "C" void kernel_launch(void* const* d_in, const int* in_sizes, int n_in,
                              void* d_out, int out_size, void* d_ws, size_t ws_size,
                              hipStream_t stream) {
  (void)in_sizes; (void)n_in; (void)out_size; (void)ws_size;
  const float* x  = (const float*)d_in[0];
  const float* Wq = (const float*)d_in[1];
  const float* Wk = (const float*)d_in[2];
  const float* Wv = (const float*)d_in[3];
  const float* Wo = (const float*)d_in[4];

  char* ws = (char*)d_ws;
  short* xb    = (short*)(ws);              // 4096x2048 bf16 (16 MiB)
  short* wqkvb = (short*)(ws + 16777216);   // 3072x2048      (12 MiB)
  short* wob   = (short*)(ws + 29360128);   // 2048x2048      (8 MiB)
  short* Qb    = (short*)(ws + 37748736);   // 4096x2048      (16 MiB)
  short* Kb    = (short*)(ws + 54525952);   // 4096x512       (4 MiB)
  short* Vtb   = (short*)(ws + 58720256);   // 2x512x2048     (4 MiB)
  short* Yb    = (short*)(ws + 62914560);   // 4096x2048      (16 MiB)

  k_f2bf<<<4096, 256, 0, stream>>>(x, xb, 1048576);
  k_f2bf<<<2048, 256, 0, stream>>>(Wq, wqkvb, 524288);
  k_f2bf<<<512, 256, 0, stream>>>(Wk, wqkvb + 4194304, 131072);
  k_f2bf<<<512, 256, 0, stream>>>(Wv, wqkvb + 5242880, 131072);
  k_f2bf<<<2048, 256, 0, stream>>>(Wo, wob, 524288);

  // fused QKV projection: N = 2048(Q) + 512(K) + 512(V) = 3072
  k_gemm_bt<3><<<dim3(24, 32), 256, 0, stream>>>(xb, wqkvb, Qb, Kb, Vtb,
                                                 4096, 3072, 2048);

  // RoPE; Q gets (1/sqrt(128))*log2(e) folded in for exp2-domain softmax
  k_rope<<<16384, 256, 0, stream>>>(Qb, 10, 2048, 0.12751758912141852f);
  k_rope<<<4096, 256, 0, stream>>>(Kb, 8, 512, 1.0f);

  k_attn3<<<dim3(16, 16, 2), 256, 0, stream>>>(Qb, Kb, Vtb, Yb);

  k_gemm_bt<1><<<dim3(16, 32), 256, 0, stream>>>(Yb, wob, d_out, nullptr,
                                                 nullptr, 4096, 2048, 2048);
}